// Round 14
// baseline (84.823 us; speedup 1.0000x reference)
//
#include <hip/hip_runtime.h>
#include <hip/hip_bf16.h>

#define N 4096
#define FIN 128
#define U0 16
#define H0 4
#define MAXD 128        // padded neighbor-list cap; P(deg>128), Binom(4096,0.01) ~ 0
#define NGEMM (N / 16)  // 256 gemm blocks
#define NCSR4 (N / 4)   // 1024 CSR blocks, 4 rows each
#define NATT  (N / 4)   // 1024 attn blocks, 4 rows each
#define FSTRIDE 32      // F row: h0[0..15], a2[16..19], pad to 128B line
#define SCOPE __HIP_MEMORY_SCOPE_AGENT

// ---------------------------------------------------------------------------
// K1 (unchanged from R12): blocks [0,256): gemm -> F lines, a1, S0 atomics
//                          blocks [256,1280): 4 adj rows -> padded CSR
// ---------------------------------------------------------------------------
__global__ void k1_fused(const float* __restrict__ adj, const float* __restrict__ x,
                         const float* __restrict__ w0, const float* __restrict__ aw1,
                         const float* __restrict__ aw2,
                         int* __restrict__ deg, int* __restrict__ cols,
                         float* __restrict__ F, float* __restrict__ a1,
                         float* __restrict__ S0) {
    const int t = threadIdx.x;
    if (blockIdx.x < NGEMM) {
        const int bid = blockIdx.x;
        __shared__ float xs[16][FIN + 1];
        __shared__ float ws[FIN][U0];
        __shared__ float hs[16][U0 + 1];
        const int r0 = bid * 16;

        for (int k = t; k < FIN * U0; k += 256) ws[k / U0][k % U0] = w0[k];
        for (int k = t; k < 16 * FIN; k += 256)
            xs[k / FIN][k % FIN] = x[(size_t)(r0 + k / FIN) * FIN + (k % FIN)];
        __syncthreads();

        const int r = t / U0, u = t % U0;
        float acc = 0.f;
        #pragma unroll 8
        for (int k = 0; k < FIN; ++k) acc += xs[r][k] * ws[k][u];
        hs[r][u] = acc;
        F[(size_t)(r0 + r) * FSTRIDE + u] = acc;          // h0 part of the line
        __syncthreads();

        if (t < 16 * H0) {                 // 64 threads: (row, head)
            const int rr = t / H0, hh = t % H0;
            float s1 = 0.f, s2 = 0.f;
            #pragma unroll
            for (int u2 = 0; u2 < U0; ++u2) {
                float hv = hs[rr][u2];
                s1 += hv * aw1[u2 * H0 + hh];
                s2 += hv * aw2[u2 * H0 + hh];
            }
            a1[(r0 + rr) * H0 + hh] = s1;
            F[(size_t)(r0 + rr) * FSTRIDE + 16 + hh] = s2; // a2 part, same line
        } else if (t >= 128 && t < 144) {  // 16 threads: column partial -> S0
            const int d = t - 128;
            float s = 0.f;
            #pragma unroll
            for (int rr = 0; rr < 16; ++rr) s += hs[rr][d];
            atomicAdd(&S0[d], s);          // 16 addresses x 256 writers: benign
        }
    } else {
        // ---------------- CSR build: 4 rows per block (2 passes of 2) --------
        const int rb4 = (blockIdx.x - NGEMM) * 4;
        const int lane = t & 63, wid = t >> 6;

        __shared__ int cls[2][MAXD];
        __shared__ int wsum[4];
        __shared__ int dgs[2];

        for (int pair = 0; pair < 2; ++pair) {
            const int rb = rb4 + pair * 2;
            const float4* __restrict__ ar0 =
                reinterpret_cast<const float4*>(adj + (size_t)rb * N);
            const float4* __restrict__ ar1 =
                reinterpret_cast<const float4*>(adj + (size_t)(rb + 1) * N);
            float4 v0[4], v1[4];
            #pragma unroll
            for (int p = 0; p < 4; ++p) v0[p] = ar0[t + 256 * p];
            #pragma unroll
            for (int p = 0; p < 4; ++p) v1[p] = ar1[t + 256 * p];

            #pragma unroll
            for (int rr = 0; rr < 2; ++rr) {
                const float4* v = rr ? v1 : v0;
                int c = 0;
                #pragma unroll
                for (int p = 0; p < 4; ++p)
                    c += (v[p].x != 0.f) + (v[p].y != 0.f) + (v[p].z != 0.f) + (v[p].w != 0.f);

                int sc = c;                      // inclusive wave scan
                #pragma unroll
                for (int s = 1; s < 64; s <<= 1) {
                    int u = __shfl_up(sc, s);
                    if (lane >= s) sc += u;
                }
                if (rr || pair) __syncthreads(); // protect wsum/cls reuse
                if (lane == 63) wsum[wid] = sc;
                __syncthreads();
                int base = 0;
                #pragma unroll
                for (int w2 = 0; w2 < 4; ++w2)
                    if (w2 < wid) base += wsum[w2];
                const int off = base + sc - c;
                if (t == 255) dgs[rr] = min(base + sc, MAXD);

                int w = off;                     // compact into LDS
                #pragma unroll
                for (int p = 0; p < 4; ++p) {
                    const int j0 = (t + 256 * p) * 4;
                    if (v[p].x != 0.f && w < MAXD) cls[rr][w++] = j0;
                    if (v[p].y != 0.f && w < MAXD) cls[rr][w++] = j0 + 1;
                    if (v[p].z != 0.f && w < MAXD) cls[rr][w++] = j0 + 2;
                    if (v[p].w != 0.f && w < MAXD) cls[rr][w++] = j0 + 3;
                }
            }
            __syncthreads();
            if (t < dgs[0]) cols[(size_t)rb * MAXD + t] = cls[0][t];
            const int t2 = t - 128;
            if (t2 >= 0 && t2 < dgs[1] && t2 < 128)
                cols[(size_t)(rb + 1) * MAXD + t2] = cls[1][t2];
            if (t < 128) {
                const int k2 = t + 128;
                if (k2 < dgs[1]) cols[(size_t)(rb + 1) * MAXD + k2] = cls[1][k2];
            }
            if (t == 0) { deg[rb] = dgs[0]; deg[rb + 1] = dgs[1]; }
        }
    }
}

// ---------------------------------------------------------------------------
// K2: attn0 + flag-barrier + attn1, one kernel.  1024 blocks, 4 rows each.
// Producers == consumers (every block writes 4 hp then waits for all), grid
// is <=50% of residency capacity (LDS 18.5KB -> 8 blocks/CU; grid needs 4/CU)
// so the internal spin-barrier cannot starve.  Flags re-armed by the memset
// node each replay (poison-safe).
// ---------------------------------------------------------------------------
__global__ __launch_bounds__(256, 4)
void attn_mega(const float* __restrict__ F, const float* __restrict__ a1,
               const float* __restrict__ S0,
               const int* __restrict__ deg, const int* __restrict__ cols,
               const float* __restrict__ w1,
               const float* __restrict__ aw11, const float* __restrict__ aw21,
               int* __restrict__ flagB, float* __restrict__ hp,
               float* __restrict__ out) {
    __shared__ int cls[4][MAXD];      // 2 KB
    __shared__ float hps[N];          // 16 KB
    __shared__ float s1red[4];
    const int b = blockIdx.x;
    const int i0 = b * 4;
    const int t = threadIdx.x;
    const int w = t >> 6, lane = t & 63;

    // ---- stage 4 rows' neighbor lists, padded with 0 ----
    for (int k = t; k < 4 * MAXD; k += 256) {
        const int row = k >> 7, idx = k & 127;
        const int dgr = deg[i0 + row];
        cls[row][idx] = (idx < dgr) ? cols[(size_t)(i0 + row) * MAXD + idx] : 0;
    }
    __syncthreads();

    const int i = i0 + w;
    const int dg = deg[i];

    // ---- attn0: one wave per row, vectorized F-line gather (R12-proven) ----
    {
        const int q = lane >> 4, r = lane & 15;
        const int hh = r >> 2, dgc = r & 3;
        const float a1v = a1[i * H0 + hh];

        float4 accn = make_float4(0.f, 0.f, 0.f, 0.f);
        float accd = 0.f;
        for (int kb = 0; kb < dg; kb += 8) {             // wave-uniform trips
            const int kA = kb + q;
            const int kB = kb + 4 + q;
            const int jA = cls[w][kA < MAXD ? kA : 0];
            const int jB = cls[w][kB < MAXD ? kB : 0];
            const float msA = (kA < dg) ? 1.f : 0.f;
            const float msB = (kB < dg) ? 1.f : 0.f;
            const float* __restrict__ fA = F + (size_t)jA * FSTRIDE;
            const float* __restrict__ fB = F + (size_t)jB * FSTRIDE;
            const float4 hA = *reinterpret_cast<const float4*>(fA + dgc * 4);
            const float a2A = fA[16 + hh];
            const float4 hB = *reinterpret_cast<const float4*>(fB + dgc * 4);
            const float a2B = fB[16 + hh];

            float ccA = a1v + a2A;
            ccA = ccA > 0.f ? ccA : 0.f;
            const float eA = (__expf(ccA) - 1.f) * msA;
            accn.x = fmaf(eA, hA.x, accn.x);
            accn.y = fmaf(eA, hA.y, accn.y);
            accn.z = fmaf(eA, hA.z, accn.z);
            accn.w = fmaf(eA, hA.w, accn.w);
            accd += eA;

            float ccB = a1v + a2B;
            ccB = ccB > 0.f ? ccB : 0.f;
            const float eB = (__expf(ccB) - 1.f) * msB;
            accn.x = fmaf(eB, hB.x, accn.x);
            accn.y = fmaf(eB, hB.y, accn.y);
            accn.z = fmaf(eB, hB.z, accn.z);
            accn.w = fmaf(eB, hB.w, accn.w);
            accd += eB;
        }
        #pragma unroll
        for (int m = 16; m <= 32; m <<= 1) {
            accn.x += __shfl_xor(accn.x, m);
            accn.y += __shfl_xor(accn.y, m);
            accn.z += __shfl_xor(accn.z, m);
            accn.w += __shfl_xor(accn.w, m);
            accd   += __shfl_xor(accd, m);
        }
        const float4 s0v = reinterpret_cast<const float4*>(S0)[dgc];
        const float4 w1v = reinterpret_cast<const float4*>(w1)[r];
        const float inv = 1.f / (accd + (float)N);
        float ox = (accn.x + s0v.x) * inv; ox = ox > 0.f ? ox : 0.f;
        float oy = (accn.y + s0v.y) * inv; oy = oy > 0.f ? oy : 0.f;
        float oz = (accn.z + s0v.z) * inv; oz = oz > 0.f ? oz : 0.f;
        float ow = (accn.w + s0v.w) * inv; ow = ow > 0.f ? ow : 0.f;
        float pv = ox * w1v.x + oy * w1v.y + oz * w1v.z + ow * w1v.w;
        #pragma unroll
        for (int m = 1; m <= 8; m <<= 1) pv += __shfl_xor(pv, m);
        if (lane == 0) hp[i] = pv;
    }

    // ---- flag barrier: release own flag, wait for all 1024 ----
    __syncthreads();                          // drain hp stores
    if (t == 0) {
        __threadfence();
        __hip_atomic_store(&flagB[b], 1, __ATOMIC_RELEASE, SCOPE);
    }
    if (w == 0) {                             // wave 0 spins, 16 flags per lane
        for (;;) {
            int v = 1;
            #pragma unroll
            for (int k = 0; k < 16; ++k)
                v &= __hip_atomic_load(&flagB[(k << 6) | lane], __ATOMIC_RELAXED, SCOPE);
            if (__all(v)) break;
            __builtin_amdgcn_s_sleep(2);
        }
    }
    __syncthreads();
    if (t == 0) __threadfence();              // acquire
    __syncthreads();

    // ---- attn1: stage hp -> LDS, S1 block-reduce, LDS gather, sigmoid ----
    {
        float s = 0.f;
        const float4* __restrict__ hp4 = reinterpret_cast<const float4*>(hp);
        #pragma unroll
        for (int k = t; k < N / 4; k += 256) {
            float4 v = hp4[k];
            reinterpret_cast<float4*>(hps)[k] = v;
            s += v.x + v.y + v.z + v.w;
        }
        #pragma unroll
        for (int o = 32; o; o >>= 1) s += __shfl_down(s, o);
        if (lane == 0) s1red[w] = s;
        __syncthreads();
        const float S1 = s1red[0] + s1red[1] + s1red[2] + s1red[3];

        const float w1s = aw11[0], w2s = aw21[0];
        const float a1v1 = hps[i] * w1s;
        float accn = 0.f, accd = 0.f;
        for (int k = lane; k < dg; k += 64) {
            const int j = cls[w][k];
            const float hj = hps[j];
            float cc = a1v1 + hj * w2s;
            cc = cc > 0.f ? cc : 0.f;
            const float e = __expf(cc) - 1.f;
            accn = fmaf(e, hj, accn);
            accd += e;
        }
        #pragma unroll
        for (int o = 32; o; o >>= 1) {
            accn += __shfl_down(accn, o);
            accd += __shfl_down(accd, o);
        }
        if (lane == 0) {
            const float v = (accn + S1) / (accd + (float)N);
            out[i] = 1.f / (1.f + __expf(-v));
        }
    }
}

// ---------------------------------------------------------------------------
extern "C" void kernel_launch(void* const* d_in, const int* in_sizes, int n_in,
                              void* d_out, int out_size, void* d_ws, size_t ws_size,
                              hipStream_t stream) {
    const float* x    = (const float*)d_in[0];
    const float* adj  = (const float*)d_in[1];
    const float* w0   = (const float*)d_in[2];
    const float* aw10 = (const float*)d_in[3];
    const float* aw20 = (const float*)d_in[4];
    const float* w1   = (const float*)d_in[5];
    const float* aw11 = (const float*)d_in[6];
    const float* aw21 = (const float*)d_in[7];
    float* out = (float*)d_out;

    char* p = (char*)d_ws;
    auto alloc = [&](size_t bytes) {
        char* r = p;
        p += (bytes + 255) & ~(size_t)255;
        return r;
    };
    float* S0    = (float*)alloc(256);                     // 16 floats used
    int*   flagB = (int*)alloc(NATT * 4);                  // 4 KB (contig w/ S0)
    float* F     = (float*)alloc((size_t)N * FSTRIDE * 4); // 512 KB fused h0+a2
    float* a1    = (float*)alloc((size_t)N * H0 * 4);
    float* hp    = (float*)alloc((size_t)N * 4);
    int*   deg   = (int*)alloc((size_t)N * 4);
    int*   cols  = (int*)alloc((size_t)N * MAXD * 4);

    hipMemsetAsync(S0, 0, 256 + NATT * 4, stream);         // zero S0 + flagB
    k1_fused<<<NGEMM + NCSR4, 256, 0, stream>>>(adj, x, w0, aw10, aw20,
                                                deg, cols, F, a1, S0);
    attn_mega<<<NATT, 256, 0, stream>>>(F, a1, S0, deg, cols, w1,
                                        aw11, aw21, flagB, hp, out);
}

// Round 15
// 34.685 us; speedup vs baseline: 2.4456x; 2.4456x over previous
//
#include <hip/hip_runtime.h>
#include <hip/hip_bf16.h>

#define N 4096
#define FIN 128
#define U0 16
#define H0 4
#define MAXD 128        // padded neighbor-list cap; P(deg>128), Binom(4096,0.01) ~ 0
#define NGEMM (N / 16)  // 256 gemm blocks
#define NATT  (N / 4)   // 1024 csr+attn0 blocks (4 rows each)
#define FSTRIDE 32      // F row: h0[0..15], a2[16..19], pad to 128B line

// ---------------------------------------------------------------------------
// K1: gemm only (tiny, fast-draining).  h0/a2 -> fused F lines, a1,
// partS0 plain stores (no atomics -> no memset node anywhere).
// ---------------------------------------------------------------------------
__global__ void k1_gemm(const float* __restrict__ x, const float* __restrict__ w0,
                        const float* __restrict__ aw1, const float* __restrict__ aw2,
                        float* __restrict__ F, float* __restrict__ a1,
                        float* __restrict__ partS0) {
    __shared__ float xs[16][FIN + 1];
    __shared__ float ws[FIN][U0];
    __shared__ float hs[16][U0 + 1];
    const int t = threadIdx.x;
    const int r0 = blockIdx.x * 16;

    for (int k = t; k < FIN * U0; k += 256) ws[k / U0][k % U0] = w0[k];
    for (int k = t; k < 16 * FIN; k += 256)
        xs[k / FIN][k % FIN] = x[(size_t)(r0 + k / FIN) * FIN + (k % FIN)];
    __syncthreads();

    const int r = t / U0, u = t % U0;
    float acc = 0.f;
    #pragma unroll 8
    for (int k = 0; k < FIN; ++k) acc += xs[r][k] * ws[k][u];
    hs[r][u] = acc;
    F[(size_t)(r0 + r) * FSTRIDE + u] = acc;          // h0 part of the line
    __syncthreads();

    if (t < 16 * H0) {                 // 64 threads: (row, head)
        const int rr = t / H0, hh = t % H0;
        float s1 = 0.f, s2 = 0.f;
        #pragma unroll
        for (int u2 = 0; u2 < U0; ++u2) {
            float hv = hs[rr][u2];
            s1 += hv * aw1[u2 * H0 + hh];
            s2 += hv * aw2[u2 * H0 + hh];
        }
        a1[(r0 + rr) * H0 + hh] = s1;
        F[(size_t)(r0 + rr) * FSTRIDE + 16 + hh] = s2; // a2 part, same line
    } else if (t >= 128 && t < 144) {  // 16 threads: column partial, plain store
        const int d = t - 128;
        float s = 0.f;
        #pragma unroll
        for (int rr = 0; rr < 16; ++rr) s += hs[rr][d];
        partS0[blockIdx.x * 16 + d] = s;
    }
}

// ---------------------------------------------------------------------------
// K2: CSR-build + attn0 fused (4 rows/block).  The block streams its 4 adj
// rows into an LDS CSR and the vectorized gather consumes it IN-LDS (no cols
// read-back).  cols/deg persisted only for attn1.  partS0 reduced per block.
// ---------------------------------------------------------------------------
__global__ void csr_attn0(const float* __restrict__ adj, const float* __restrict__ F,
                          const float* __restrict__ a1, const float* __restrict__ partS0,
                          const float* __restrict__ w1,
                          int* __restrict__ deg, int* __restrict__ cols,
                          float* __restrict__ hp) {
    __shared__ int   cls[4][MAXD];    // 2 KB
    __shared__ int   wsum[4];
    __shared__ int   dgs[4];
    __shared__ float red[16][17];
    __shared__ float s0s[16];

    const int t = threadIdx.x;
    const int wid = t >> 6, lane = t & 63;
    const int i0 = blockIdx.x * 4;

    // ---- partS0 [256][16] -> s0s[16] (L2-hot, ~1us) ----
    {
        const int d = t & 15, ch = t >> 4;
        float s = 0.f;
        #pragma unroll
        for (int k = ch; k < 256; k += 16) s += partS0[k * 16 + d];
        red[ch][d] = s;
    }
    __syncthreads();
    if (t < 16) {
        float s2 = 0.f;
        #pragma unroll
        for (int k = 0; k < 16; ++k) s2 += red[k][t];
        s0s[t] = s2;
    }

    // ---- stream 4 adj rows -> LDS CSR (2 passes of 2 rows) ----
    for (int pair = 0; pair < 2; ++pair) {
        const int rb = i0 + pair * 2;
        const float4* __restrict__ ar0 =
            reinterpret_cast<const float4*>(adj + (size_t)rb * N);
        const float4* __restrict__ ar1 =
            reinterpret_cast<const float4*>(adj + (size_t)(rb + 1) * N);
        float4 v0[4], v1[4];
        #pragma unroll
        for (int p = 0; p < 4; ++p) v0[p] = ar0[t + 256 * p];
        #pragma unroll
        for (int p = 0; p < 4; ++p) v1[p] = ar1[t + 256 * p];

        #pragma unroll
        for (int rr = 0; rr < 2; ++rr) {
            const float4* v = rr ? v1 : v0;
            const int row = pair * 2 + rr;
            int c = 0;
            #pragma unroll
            for (int p = 0; p < 4; ++p)
                c += (v[p].x != 0.f) + (v[p].y != 0.f) + (v[p].z != 0.f) + (v[p].w != 0.f);

            int sc = c;                      // inclusive wave scan (6 shfl steps)
            #pragma unroll
            for (int s = 1; s < 64; s <<= 1) {
                int u = __shfl_up(sc, s);
                if (lane >= s) sc += u;
            }
            __syncthreads();                 // wsum (and s0s on first iter) safe
            if (lane == 63) wsum[wid] = sc;
            __syncthreads();
            int base = 0;
            #pragma unroll
            for (int w2 = 0; w2 < 4; ++w2)
                if (w2 < wid) base += wsum[w2];
            const int off = base + sc - c;
            if (t == 255) dgs[row] = min(base + sc, MAXD);

            int w = off;                     // compact into LDS
            #pragma unroll
            for (int p = 0; p < 4; ++p) {
                const int j0 = (t + 256 * p) * 4;
                if (v[p].x != 0.f && w < MAXD) cls[row][w++] = j0;
                if (v[p].y != 0.f && w < MAXD) cls[row][w++] = j0 + 1;
                if (v[p].z != 0.f && w < MAXD) cls[row][w++] = j0 + 2;
                if (v[p].w != 0.f && w < MAXD) cls[row][w++] = j0 + 3;
            }
        }
    }
    __syncthreads();

    // ---- zero-pad cls tails (masked gather lanes must index valid rows) ----
    // and persist cols/deg for attn1 (stores are fire-and-forget)
    for (int k = t; k < 4 * MAXD; k += 256) {
        const int row = k >> 7, idx = k & 127;
        if (idx < dgs[row]) cols[(size_t)(i0 + row) * MAXD + idx] = cls[row][idx];
        else                cls[row][idx] = 0;
    }
    if (t < 4) deg[i0 + t] = dgs[t];
    __syncthreads();

    // ---- attn0: one wave per row, vectorized F-line gather (R12-proven) ----
    const int i = i0 + wid;
    const int dg = dgs[wid];
    const int q = lane >> 4, r = lane & 15;
    const int hh = r >> 2, dgc = r & 3;
    const float a1v = a1[i * H0 + hh];

    float4 accn = make_float4(0.f, 0.f, 0.f, 0.f);
    float accd = 0.f;
    for (int kb = 0; kb < dg; kb += 8) {             // wave-uniform trip count
        const int kA = kb + q;
        const int kB = kb + 4 + q;
        const int jA = cls[wid][kA < MAXD ? kA : 0];
        const int jB = cls[wid][kB < MAXD ? kB : 0];
        const float msA = (kA < dg) ? 1.f : 0.f;
        const float msB = (kB < dg) ? 1.f : 0.f;
        const float* __restrict__ fA = F + (size_t)jA * FSTRIDE;
        const float* __restrict__ fB = F + (size_t)jB * FSTRIDE;
        const float4 hA = *reinterpret_cast<const float4*>(fA + dgc * 4);
        const float a2A = fA[16 + hh];
        const float4 hB = *reinterpret_cast<const float4*>(fB + dgc * 4);
        const float a2B = fB[16 + hh];

        float ccA = a1v + a2A;
        ccA = ccA > 0.f ? ccA : 0.f;
        const float eA = (__expf(ccA) - 1.f) * msA;
        accn.x = fmaf(eA, hA.x, accn.x);
        accn.y = fmaf(eA, hA.y, accn.y);
        accn.z = fmaf(eA, hA.z, accn.z);
        accn.w = fmaf(eA, hA.w, accn.w);
        accd += eA;

        float ccB = a1v + a2B;
        ccB = ccB > 0.f ? ccB : 0.f;
        const float eB = (__expf(ccB) - 1.f) * msB;
        accn.x = fmaf(eB, hB.x, accn.x);
        accn.y = fmaf(eB, hB.y, accn.y);
        accn.z = fmaf(eB, hB.z, accn.z);
        accn.w = fmaf(eB, hB.w, accn.w);
        accd += eB;
    }
    #pragma unroll
    for (int m = 16; m <= 32; m <<= 1) {
        accn.x += __shfl_xor(accn.x, m);
        accn.y += __shfl_xor(accn.y, m);
        accn.z += __shfl_xor(accn.z, m);
        accn.w += __shfl_xor(accn.w, m);
        accd   += __shfl_xor(accd, m);
    }
    const float4 s0v = reinterpret_cast<const float4*>(s0s)[dgc];
    const float4 w1v = reinterpret_cast<const float4*>(w1)[r];
    const float inv = 1.f / (accd + (float)N);
    float ox = (accn.x + s0v.x) * inv; ox = ox > 0.f ? ox : 0.f;
    float oy = (accn.y + s0v.y) * inv; oy = oy > 0.f ? oy : 0.f;
    float oz = (accn.z + s0v.z) * inv; oz = oz > 0.f ? oz : 0.f;
    float ow = (accn.w + s0v.w) * inv; ow = ow > 0.f ? ow : 0.f;
    float pv = ox * w1v.x + oy * w1v.y + oz * w1v.z + ow * w1v.w;
    #pragma unroll
    for (int m = 1; m <= 8; m <<= 1) pv += __shfl_xor(pv, m);
    if (lane == 0) hp[i] = pv;
}

// ---------------------------------------------------------------------------
// K3: layer-1 sparse attention + sigmoid -> out [4096].  (R12-proven)
// Stages all of hp (16 KB) into LDS; S1 free block-reduce; LDS gather.
// ---------------------------------------------------------------------------
__global__ void attn1(const float* __restrict__ hp,
                      const float* __restrict__ aw11, const float* __restrict__ aw21,
                      const int* __restrict__ deg, const int* __restrict__ cols,
                      float* __restrict__ out) {
    __shared__ float hps[N];          // 16 KB
    __shared__ int cls[4][MAXD];      // 2 KB
    __shared__ float s1red[4];
    const int t = threadIdx.x;
    const int w = t >> 6, lane = t & 63;
    const int i0 = blockIdx.x * 4;

    float s = 0.f;
    const float4* __restrict__ hp4 = reinterpret_cast<const float4*>(hp);
    #pragma unroll
    for (int k = t; k < N / 4; k += 256) {
        float4 v = hp4[k];
        reinterpret_cast<float4*>(hps)[k] = v;
        s += v.x + v.y + v.z + v.w;
    }
    for (int k = t; k < 4 * MAXD; k += 256)
        cls[k >> 7][k & 127] = cols[(size_t)(i0 + (k >> 7)) * MAXD + (k & 127)];

    #pragma unroll
    for (int o = 32; o; o >>= 1) s += __shfl_down(s, o);
    if (lane == 0) s1red[w] = s;
    __syncthreads();
    const float S1 = s1red[0] + s1red[1] + s1red[2] + s1red[3];

    const int i = i0 + w;
    const float w1v = aw11[0], w2v = aw21[0];
    const float a1v = hps[i] * w1v;
    const int dg = deg[i];

    float accn = 0.f, accd = 0.f;
    for (int k = lane; k < dg; k += 64) {
        const int j = cls[w][k];
        const float hj = hps[j];
        float cc = a1v + hj * w2v;
        cc = cc > 0.f ? cc : 0.f;
        const float e = __expf(cc) - 1.f;
        accn = fmaf(e, hj, accn);
        accd += e;
    }
    #pragma unroll
    for (int o = 32; o; o >>= 1) {
        accn += __shfl_down(accn, o);
        accd += __shfl_down(accd, o);
    }
    if (lane == 0) {
        const float v = (accn + S1) / (accd + (float)N);
        out[i] = 1.f / (1.f + __expf(-v));
    }
}

// ---------------------------------------------------------------------------
extern "C" void kernel_launch(void* const* d_in, const int* in_sizes, int n_in,
                              void* d_out, int out_size, void* d_ws, size_t ws_size,
                              hipStream_t stream) {
    const float* x    = (const float*)d_in[0];
    const float* adj  = (const float*)d_in[1];
    const float* w0   = (const float*)d_in[2];
    const float* aw10 = (const float*)d_in[3];
    const float* aw20 = (const float*)d_in[4];
    const float* w1   = (const float*)d_in[5];
    const float* aw11 = (const float*)d_in[6];
    const float* aw21 = (const float*)d_in[7];
    float* out = (float*)d_out;

    char* p = (char*)d_ws;
    auto alloc = [&](size_t bytes) {
        char* r = p;
        p += (bytes + 255) & ~(size_t)255;
        return r;
    };
    float* partS0 = (float*)alloc(NGEMM * 16 * 4);          // 16 KB
    float* F      = (float*)alloc((size_t)N * FSTRIDE * 4); // 512 KB fused h0+a2
    float* a1     = (float*)alloc((size_t)N * H0 * 4);
    float* hp     = (float*)alloc((size_t)N * 4);
    int*   deg    = (int*)alloc((size_t)N * 4);
    int*   cols   = (int*)alloc((size_t)N * MAXD * 4);

    k1_gemm<<<NGEMM, 256, 0, stream>>>(x, w0, aw10, aw20, F, a1, partS0);
    csr_attn0<<<NATT, 256, 0, stream>>>(adj, F, a1, partS0, w1, deg, cols, hp);
    attn1<<<NATT, 256, 0, stream>>>(hp, aw11, aw21, deg, cols, out);
}